// Round 2
// baseline (278.078 us; speedup 1.0000x reference)
//
#include <hip/hip_runtime.h>

// EdgeVar: mean over graphs of mean over edges of (||pos[dst]-pos[src]|| - 1)^2,
// edges grouped by batch_ids[src]. G=1024 bins, E=12.8M, N=200k.
//
// Structure:
//   1. pack_nodes: {pos.x, pos.y, batch} -> 16B records in d_ws (1 gather saved/edge)
//   2. edge_accum: per-block LDS histogram (1024 sums + 1024 counts), global atomic flush
//   3. finalize:   mean(gsum / max(gcnt,1)) -> d_out[0]

#define GBINS 1024

// clang ext-vector type: __builtin_nontemporal_load requires scalar/ext-vector,
// not HIP's struct-based int4.
typedef int iv4 __attribute__((ext_vector_type(4)));

__global__ void pack_nodes(const float2* __restrict__ pos,
                           const int* __restrict__ batch,
                           float4* __restrict__ rec, int N) {
    int i = blockIdx.x * blockDim.x + threadIdx.x;
    if (i < N) {
        float2 p = pos[i];
        rec[i] = make_float4(p.x, p.y, __int_as_float(batch[i]), 0.f);
    }
}

template <bool PACKED>
__global__ __launch_bounds__(1024)
void edge_accum(const float4* __restrict__ rec,
                const float2* __restrict__ pos,
                const int* __restrict__ batch,
                const int* __restrict__ src,
                const int* __restrict__ dst,
                float* __restrict__ gsum, float* __restrict__ gcnt, int E) {
    __shared__ float ls[GBINS];   // per-graph sum of (eu-1)^2
    __shared__ float lc[GBINS];   // per-graph edge count
    for (int i = threadIdx.x; i < GBINS; i += blockDim.x) { ls[i] = 0.f; lc[i] = 0.f; }
    __syncthreads();

    const int tid    = blockIdx.x * blockDim.x + threadIdx.x;
    const int stride = gridDim.x * blockDim.x;
    const int E4     = E >> 2;
    const iv4* __restrict__ s4 = (const iv4*)src;
    const iv4* __restrict__ d4 = (const iv4*)dst;

    auto proc = [&](int s, int d) {
        float ax, ay, bx, by; int g;
        if constexpr (PACKED) {
            float4 a = rec[s];                       // 16B: x, y, batch-bits, pad
            float2 b = ((const float2*)rec)[2 * d];  // 8B: x, y (same line as full rec)
            ax = a.x; ay = a.y; g = __float_as_int(a.z);
            bx = b.x; by = b.y;
        } else {
            float2 a = pos[s]; float2 b = pos[d]; g = batch[s];
            ax = a.x; ay = a.y; bx = b.x; by = b.y;
        }
        float dx = bx - ax, dy = by - ay;
        float eu = sqrtf(fmaf(dx, dx, dy * dy));
        float t  = eu - 1.f;
        atomicAdd(&ls[g], t * t);   // ds_add_f32; random bins over 32 banks ~2-way (free)
        atomicAdd(&lc[g], 1.f);
    };

    // 4 edges per thread per iteration; index streams are non-temporal so the
    // 102 MB stream doesn't evict the 3.2 MB node table from L2.
    for (int i = tid; i < E4; i += stride) {
        iv4 s = __builtin_nontemporal_load(&s4[i]);
        iv4 d = __builtin_nontemporal_load(&d4[i]);
        proc(s.x, d.x); proc(s.y, d.y); proc(s.z, d.z); proc(s.w, d.w);
    }
    for (int i = (E4 << 2) + tid; i < E; i += stride) {  // tail (E%4 != 0 safety)
        proc(src[i], dst[i]);
    }

    __syncthreads();
    for (int g = threadIdx.x; g < GBINS; g += blockDim.x) {
        float c = lc[g];
        if (c != 0.f) {                 // skip empty bins: fewer global atomics
            atomicAdd(&gsum[g], ls[g]);
            atomicAdd(&gcnt[g], c);
        }
    }
}

__global__ void finalize_kernel(const float* __restrict__ gsum,
                                const float* __restrict__ gcnt,
                                float* __restrict__ out,
                                const int* __restrict__ nG_ptr) {
    const int G = *nG_ptr;
    float v = 0.f;
    for (int g = threadIdx.x; g < G; g += blockDim.x)
        v += gsum[g] / fmaxf(gcnt[g], 1.f);

    __shared__ float w[16];
    for (int off = 32; off; off >>= 1) v += __shfl_down(v, off, 64);
    if ((threadIdx.x & 63) == 0) w[threadIdx.x >> 6] = v;
    __syncthreads();
    if (threadIdx.x == 0) {
        float s = 0.f;
        int nw = (blockDim.x + 63) >> 6;
        for (int i = 0; i < nw; ++i) s += w[i];
        out[0] = s / (float)G;
    }
}

extern "C" void kernel_launch(void* const* d_in, const int* in_sizes, int n_in,
                              void* d_out, int out_size, void* d_ws, size_t ws_size,
                              hipStream_t stream) {
    const float2* pos   = (const float2*)d_in[0];   // node_pos [N,2] f32
    const int*    ei    = (const int*)d_in[1];      // edge_index [2,E] -> int32
    const int*    batch = (const int*)d_in[2];      // batch_ids [N] -> int32
    const int*    nG    = (const int*)d_in[3];      // num_graphs scalar

    const int N = in_sizes[0] / 2;
    const int E = in_sizes[1] / 2;
    const int* src = ei;
    const int* dst = ei + E;

    float*  gsum = (float*)d_ws;
    float*  gcnt = gsum + GBINS;
    float4* rec  = (float4*)((char*)d_ws + 2 * GBINS * sizeof(float));
    const size_t need = 2 * GBINS * sizeof(float) + (size_t)N * sizeof(float4);
    const bool packed = (ws_size >= need);

    // d_ws is re-poisoned to 0xAA before every timed launch — zero the bins.
    (void)hipMemsetAsync(d_ws, 0, 2 * GBINS * sizeof(float), stream);

    if (packed) {
        pack_nodes<<<(N + 255) / 256, 256, 0, stream>>>(pos, batch, rec, N);
        edge_accum<true><<<512, 1024, 0, stream>>>(rec, pos, batch, src, dst, gsum, gcnt, E);
    } else {
        edge_accum<false><<<512, 1024, 0, stream>>>(rec, pos, batch, src, dst, gsum, gcnt, E);
    }
    finalize_kernel<<<1, 1024, 0, stream>>>(gsum, gcnt, (float*)d_out, nG);
}